// Round 1
// baseline (90.153 us; speedup 1.0000x reference)
//
#include <hip/hip_runtime.h>

#define PP   1024
#define MM   64
#define RR   32
#define ROWS 4            // rows per block in main kernel
#define TPB  512          // threads per block (8 waves)
#define NW   (TPB / 64)   // 8 waves
#define JPT  (PP / TPB)   // 2 columns per thread

// Kernel 1: per-row projections.
//   ws[p]        = dot(hidden[p,:], w_hi) + b_att      (hib)
//   ws[PP + p]   = dot(hidden[p,:], w_nei)             (hn)
__global__ __launch_bounds__(256) void proj_kernel(
    const float* __restrict__ hidden,
    const float* __restrict__ W_att,
    const float* __restrict__ b_att,
    float* __restrict__ ws)
{
    const int wid  = threadIdx.x >> 6;
    const int lane = threadIdx.x & 63;
    const int p = blockIdx.x * 4 + wid;

    float h = hidden[p * MM + lane];
    float a = h * W_att[RR + lane];        // w_hi
    float b = h * W_att[RR + MM + lane];   // w_nei
#pragma unroll
    for (int off = 32; off > 0; off >>= 1) {
        a += __shfl_down(a, off, 64);
        b += __shfl_down(b, off, 64);
    }
    if (lane == 0) {
        ws[p]      = a + b_att[0];
        ws[PP + p] = b;
    }
}

// Kernel 2: fused scores + softmax + masked weighted sum for ROWS rows.
__global__ __launch_bounds__(TPB, 2) void social_kernel(
    const float* __restrict__ hidden,
    const float* __restrict__ corr,
    const int*   __restrict__ nei,
    const float* __restrict__ W_rela,
    const float* __restrict__ b_rela,
    const float* __restrict__ W_att,
    const float* __restrict__ ws,
    float* __restrict__ out)
{
    __shared__ float4 q4[PP];            // 16 KB: per-j float4 over the 4 rows
    __shared__ float4 red[NW];           // cross-wave reduce scratch
    __shared__ float  partf[NW][ROWS][MM]; // 8 KB: phase-C partials

    const int t    = threadIdx.x;
    const int lane = t & 63;
    const int wid  = t >> 6;
    const int i0   = blockIdx.x * ROWS;

    // ---- load the 128 wave-uniform coefficients into registers ----
    float4 W0[RR / 4], W1[RR / 4], Bv[RR / 4], Wr[RR / 4];
    {
        const float4* W_rela4 = (const float4*)W_rela;  // (2,32) row-major
        const float4* b4      = (const float4*)b_rela;
        const float4* wa4     = (const float4*)W_att;   // first 32 = w_r
#pragma unroll
        for (int k = 0; k < RR / 4; ++k) {
            W0[k] = W_rela4[k];
            W1[k] = W_rela4[RR / 4 + k];
            Bv[k] = b4[k];
            Wr[k] = wa4[k];
        }
    }
    float hib[ROWS];
#pragma unroll
    for (int r = 0; r < ROWS; ++r) hib[r] = ws[i0 + r];

    // ---- Phase A: scores / pos for j = t, t + TPB ----
    float posv[JPT][ROWS];
    float mskv[JPT][ROWS];
#pragma unroll
    for (int jj = 0; jj < JPT; ++jj) {
        const int j = t + jj * TPB;
        const float hn = ws[PP + j];
#pragma unroll
        for (int r = 0; r < ROWS; ++r) {
            const int row = i0 + r;
            const float2 c = ((const float2*)corr)[row * PP + j];
            const int nv = nei[row * PP + j];
            float s = 0.f;
#pragma unroll
            for (int k = 0; k < RR / 4; ++k) {
                float t0 = fmaxf(fmaf(c.x, W0[k].x, fmaf(c.y, W1[k].x, Bv[k].x)), 0.f);
                float t1 = fmaxf(fmaf(c.x, W0[k].y, fmaf(c.y, W1[k].y, Bv[k].y)), 0.f);
                float t2 = fmaxf(fmaf(c.x, W0[k].z, fmaf(c.y, W1[k].z, Bv[k].z)), 0.f);
                float t3 = fmaxf(fmaf(c.x, W0[k].w, fmaf(c.y, W1[k].w, Bv[k].w)), 0.f);
                s = fmaf(t0, Wr[k].x, s);
                s = fmaf(t1, Wr[k].y, s);
                s = fmaf(t2, Wr[k].z, s);
                s = fmaf(t3, Wr[k].w, s);
            }
            const float score = s + hib[r] + hn;
            float pos = (nv > 0) ? score : 0.0f;
            pos = (pos == 0.0f) ? -1e-6f : pos;   // exact reference semantics
            posv[jj][r] = pos;
            mskv[jj][r] = (nv > 0) ? 1.0f : 0.0f;
        }
    }

    // ---- Phase B: row softmax (over ALL 1024 entries) ----
    float m4[ROWS];
#pragma unroll
    for (int r = 0; r < ROWS; ++r) {
        float m = posv[0][r];
#pragma unroll
        for (int jj = 1; jj < JPT; ++jj) m = fmaxf(m, posv[jj][r]);
        m4[r] = m;
    }
#pragma unroll
    for (int off = 32; off > 0; off >>= 1) {
#pragma unroll
        for (int r = 0; r < ROWS; ++r)
            m4[r] = fmaxf(m4[r], __shfl_xor(m4[r], off, 64));
    }
    if (lane == 0) red[wid] = make_float4(m4[0], m4[1], m4[2], m4[3]);
    __syncthreads();
#pragma unroll
    for (int w = 0; w < NW; ++w) {
        const float4 v = red[w];
        m4[0] = fmaxf(m4[0], v.x);
        m4[1] = fmaxf(m4[1], v.y);
        m4[2] = fmaxf(m4[2], v.z);
        m4[3] = fmaxf(m4[3], v.w);
    }

    float e[JPT][ROWS];
    float s4[ROWS] = {0.f, 0.f, 0.f, 0.f};
#pragma unroll
    for (int jj = 0; jj < JPT; ++jj) {
#pragma unroll
        for (int r = 0; r < ROWS; ++r) {
            const float ev = __expf(posv[jj][r] - m4[r]);
            e[jj][r] = ev;
            s4[r] += ev;   // denominator includes masked entries
        }
    }
#pragma unroll
    for (int off = 32; off > 0; off >>= 1) {
#pragma unroll
        for (int r = 0; r < ROWS; ++r)
            s4[r] += __shfl_xor(s4[r], off, 64);
    }
    __syncthreads();   // everyone done reading red (max) before overwrite
    if (lane == 0) red[wid] = make_float4(s4[0], s4[1], s4[2], s4[3]);
    __syncthreads();
    {
        float a0 = 0.f, a1 = 0.f, a2 = 0.f, a3 = 0.f;
#pragma unroll
        for (int w = 0; w < NW; ++w) {
            const float4 v = red[w];
            a0 += v.x; a1 += v.y; a2 += v.z; a3 += v.w;
        }
        s4[0] = a0; s4[1] = a1; s4[2] = a2; s4[3] = a3;
    }
    float inv[ROWS];
#pragma unroll
    for (int r = 0; r < ROWS; ++r) inv[r] = 1.0f / s4[r];

    // store masked, normalized weights q (float4 per j -> ds_write_b128)
#pragma unroll
    for (int jj = 0; jj < JPT; ++jj) {
        const int j = t + jj * TPB;
        q4[j] = make_float4(e[jj][0] * mskv[jj][0] * inv[0],
                            e[jj][1] * mskv[jj][1] * inv[1],
                            e[jj][2] * mskv[jj][2] * inv[2],
                            e[jj][3] * mskv[jj][3] * inv[3]);
    }
    __syncthreads();

    // ---- Phase C: out[i0+r, m] = sum_j q[j][r] * hidden[j, m] ----
    const int m = lane;        // column
    const int g = wid;         // wave's j-stripe
    float acc[ROWS] = {0.f, 0.f, 0.f, 0.f};
#pragma unroll 4
    for (int j = g; j < PP; j += NW) {
        const float4 q = q4[j];          // broadcast within wave
        const float h = hidden[j * MM + m];
        acc[0] = fmaf(q.x, h, acc[0]);
        acc[1] = fmaf(q.y, h, acc[1]);
        acc[2] = fmaf(q.z, h, acc[2]);
        acc[3] = fmaf(q.w, h, acc[3]);
    }
#pragma unroll
    for (int r = 0; r < ROWS; ++r) partf[g][r][m] = acc[r];
    __syncthreads();

    if (t < ROWS * MM) {
        const int row = t >> 6;
        const int col = t & 63;
        float s = 0.f;
#pragma unroll
        for (int w = 0; w < NW; ++w) s += partf[w][row][col];
        out[(i0 + row) * MM + col] = s;
    }
}

extern "C" void kernel_launch(void* const* d_in, const int* in_sizes, int n_in,
                              void* d_out, int out_size, void* d_ws, size_t ws_size,
                              hipStream_t stream)
{
    const float* hidden = (const float*)d_in[0];
    const float* corr   = (const float*)d_in[1];
    const int*   nei    = (const int*)d_in[2];
    const float* W_rela = (const float*)d_in[3];
    const float* b_rela = (const float*)d_in[4];
    const float* W_att  = (const float*)d_in[5];
    const float* b_att  = (const float*)d_in[6];
    float* ws  = (float*)d_ws;
    float* out = (float*)d_out;

    proj_kernel<<<PP / 4, 256, 0, stream>>>(hidden, W_att, b_att, ws);
    social_kernel<<<PP / ROWS, TPB, 0, stream>>>(hidden, corr, nei, W_rela,
                                                 b_rela, W_att, ws, out);
}

// Round 2
// 86.865 us; speedup vs baseline: 1.0379x; 1.0379x over previous
//
#include <hip/hip_runtime.h>

#define PP   1024
#define MM   64
#define RR   32
#define ROWS 4            // rows per block in main kernel
#define TPB  1024         // threads per block (16 waves)
#define NW   (TPB / 64)   // 16 waves

// Kernel 1: per-row projections.
//   ws[p]        = dot(hidden[p,:], w_hi) + b_att      (hib)
//   ws[PP + p]   = dot(hidden[p,:], w_nei)             (hn)
__global__ __launch_bounds__(256) void proj_kernel(
    const float* __restrict__ hidden,
    const float* __restrict__ W_att,
    const float* __restrict__ b_att,
    float* __restrict__ ws)
{
    const int wid  = threadIdx.x >> 6;
    const int lane = threadIdx.x & 63;
    const int p = blockIdx.x * 4 + wid;

    float h = hidden[p * MM + lane];
    float a = h * W_att[RR + lane];        // w_hi
    float b = h * W_att[RR + MM + lane];   // w_nei
#pragma unroll
    for (int off = 32; off > 0; off >>= 1) {
        a += __shfl_down(a, off, 64);
        b += __shfl_down(b, off, 64);
    }
    if (lane == 0) {
        ws[p]      = a + b_att[0];
        ws[PP + p] = b;
    }
}

// Kernel 2: fused scores + softmax + masked weighted sum for ROWS rows.
// One block per 4 rows; 1024 threads (16 waves) -> thread t owns column j=t.
__global__ __launch_bounds__(TPB, 4) void social_kernel(
    const float* __restrict__ hidden,
    const float* __restrict__ corr,
    const int*   __restrict__ nei,
    const float* __restrict__ W_rela,
    const float* __restrict__ b_rela,
    const float* __restrict__ W_att,
    const float* __restrict__ ws,
    float* __restrict__ out)
{
    __shared__ float4 q4[PP];              // 16 KB: per-j weights over 4 rows
    __shared__ float4 red[NW];             // cross-wave reduce scratch
    __shared__ float  partf[NW][ROWS][MM]; // 16 KB: phase-C partials

    const int t    = threadIdx.x;
    const int lane = t & 63;
    const int wid  = t >> 6;
    const int i0   = blockIdx.x * ROWS;

    // ---- wave-uniform coefficients in registers ----
    float4 W0[RR / 4], W1[RR / 4], Bv[RR / 4], Wr[RR / 4];
    {
        const float4* W_rela4 = (const float4*)W_rela;  // (2,32) row-major
        const float4* b4      = (const float4*)b_rela;
        const float4* wa4     = (const float4*)W_att;   // first 32 = w_r
#pragma unroll
        for (int k = 0; k < RR / 4; ++k) {
            W0[k] = W_rela4[k];
            W1[k] = W_rela4[RR / 4 + k];
            Bv[k] = b4[k];
            Wr[k] = wa4[k];
        }
    }
    float hib[ROWS];
#pragma unroll
    for (int r = 0; r < ROWS; ++r) hib[r] = ws[i0 + r];

    // ---- Phase A: scores for column j = t, all 4 rows ----
    const int j = t;
    const float hn = ws[PP + j];

    float2 c[ROWS];
    int    nv[ROWS];
#pragma unroll
    for (int r = 0; r < ROWS; ++r) {
        c[r]  = ((const float2*)corr)[(i0 + r) * PP + j];
        nv[r] = nei[(i0 + r) * PP + j];
    }

    float pos[ROWS], msk[ROWS];
#pragma unroll
    for (int r = 0; r < ROWS; ++r) {
        float s = 0.f;
#pragma unroll
        for (int k = 0; k < RR / 4; ++k) {
            float t0 = fmaxf(fmaf(c[r].x, W0[k].x, fmaf(c[r].y, W1[k].x, Bv[k].x)), 0.f);
            float t1 = fmaxf(fmaf(c[r].x, W0[k].y, fmaf(c[r].y, W1[k].y, Bv[k].y)), 0.f);
            float t2 = fmaxf(fmaf(c[r].x, W0[k].z, fmaf(c[r].y, W1[k].z, Bv[k].z)), 0.f);
            float t3 = fmaxf(fmaf(c[r].x, W0[k].w, fmaf(c[r].y, W1[k].w, Bv[k].w)), 0.f);
            s = fmaf(t0, Wr[k].x, s);
            s = fmaf(t1, Wr[k].y, s);
            s = fmaf(t2, Wr[k].z, s);
            s = fmaf(t3, Wr[k].w, s);
        }
        const float score = s + hib[r] + hn;
        float p = (nv[r] > 0) ? score : 0.0f;
        p = (p == 0.0f) ? -1e-6f : p;          // exact reference semantics
        pos[r] = p;
        msk[r] = (nv[r] > 0) ? 1.0f : 0.0f;
    }

    // ---- Phase B: softmax over all 1024 j per row ----
    float m4[ROWS];
#pragma unroll
    for (int r = 0; r < ROWS; ++r) m4[r] = pos[r];
#pragma unroll
    for (int off = 32; off > 0; off >>= 1) {
#pragma unroll
        for (int r = 0; r < ROWS; ++r)
            m4[r] = fmaxf(m4[r], __shfl_xor(m4[r], off, 64));
    }
    if (lane == 0) red[wid] = make_float4(m4[0], m4[1], m4[2], m4[3]);
    __syncthreads();
#pragma unroll
    for (int w = 0; w < NW; ++w) {
        const float4 v = red[w];
        m4[0] = fmaxf(m4[0], v.x);
        m4[1] = fmaxf(m4[1], v.y);
        m4[2] = fmaxf(m4[2], v.z);
        m4[3] = fmaxf(m4[3], v.w);
    }

    float e4[ROWS], s4[ROWS];
#pragma unroll
    for (int r = 0; r < ROWS; ++r) {
        e4[r] = __expf(pos[r] - m4[r]);
        s4[r] = e4[r];                 // denominator includes masked entries
    }
#pragma unroll
    for (int off = 32; off > 0; off >>= 1) {
#pragma unroll
        for (int r = 0; r < ROWS; ++r)
            s4[r] += __shfl_xor(s4[r], off, 64);
    }
    __syncthreads();   // all reads of red (max) done before overwrite
    if (lane == 0) red[wid] = make_float4(s4[0], s4[1], s4[2], s4[3]);
    __syncthreads();
    {
        float a0 = 0.f, a1 = 0.f, a2 = 0.f, a3 = 0.f;
#pragma unroll
        for (int w = 0; w < NW; ++w) {
            const float4 v = red[w];
            a0 += v.x; a1 += v.y; a2 += v.z; a3 += v.w;
        }
        s4[0] = a0; s4[1] = a1; s4[2] = a2; s4[3] = a3;
    }

    // masked normalized weights, float4 per j (ds_write_b128)
    q4[j] = make_float4(e4[0] * msk[0] / s4[0],
                        e4[1] * msk[1] / s4[1],
                        e4[2] * msk[2] / s4[2],
                        e4[3] * msk[3] / s4[3]);
    __syncthreads();

    // ---- Phase C: out[i0+r, m] = sum_j q[j][r] * hidden[j, m] ----
    // Quarter-wave decomposition: 16 lanes cover the 64 columns as float4;
    // the 4 quarter-waves of each wave process 4 different j simultaneously.
    const int q_idx = lane >> 4;       // which quarter (j offset)
    const int mslot = lane & 15;       // float4 column slot
    float4 acc[ROWS];
#pragma unroll
    for (int r = 0; r < ROWS; ++r) acc[r] = make_float4(0.f, 0.f, 0.f, 0.f);

#pragma unroll 4
    for (int it = 0; it < 16; ++it) {
        const int jj = wid * 4 + q_idx + it * 64;
        const float4 h4 = ((const float4*)hidden)[jj * (MM / 4) + mslot];
        const float4 q  = q4[jj];
        acc[0].x = fmaf(q.x, h4.x, acc[0].x);
        acc[0].y = fmaf(q.x, h4.y, acc[0].y);
        acc[0].z = fmaf(q.x, h4.z, acc[0].z);
        acc[0].w = fmaf(q.x, h4.w, acc[0].w);
        acc[1].x = fmaf(q.y, h4.x, acc[1].x);
        acc[1].y = fmaf(q.y, h4.y, acc[1].y);
        acc[1].z = fmaf(q.y, h4.z, acc[1].z);
        acc[1].w = fmaf(q.y, h4.w, acc[1].w);
        acc[2].x = fmaf(q.z, h4.x, acc[2].x);
        acc[2].y = fmaf(q.z, h4.y, acc[2].y);
        acc[2].z = fmaf(q.z, h4.z, acc[2].z);
        acc[2].w = fmaf(q.z, h4.w, acc[2].w);
        acc[3].x = fmaf(q.w, h4.x, acc[3].x);
        acc[3].y = fmaf(q.w, h4.y, acc[3].y);
        acc[3].z = fmaf(q.w, h4.z, acc[3].z);
        acc[3].w = fmaf(q.w, h4.w, acc[3].w);
    }

    // reduce the 4 quarter-waves (same mslot, different j subsets)
#pragma unroll
    for (int off = 16; off <= 32; off <<= 1) {
#pragma unroll
        for (int r = 0; r < ROWS; ++r) {
            acc[r].x += __shfl_xor(acc[r].x, off, 64);
            acc[r].y += __shfl_xor(acc[r].y, off, 64);
            acc[r].z += __shfl_xor(acc[r].z, off, 64);
            acc[r].w += __shfl_xor(acc[r].w, off, 64);
        }
    }
    if (lane < 16) {
#pragma unroll
        for (int r = 0; r < ROWS; ++r)
            ((float4*)&partf[wid][r][0])[mslot] = acc[r];
    }
    __syncthreads();

    if (t < ROWS * MM) {
        const int row = t >> 6;
        const int col = t & 63;
        float s = 0.f;
#pragma unroll
        for (int w = 0; w < NW; ++w) s += partf[w][row][col];
        out[(i0 + row) * MM + col] = s;
    }
}

extern "C" void kernel_launch(void* const* d_in, const int* in_sizes, int n_in,
                              void* d_out, int out_size, void* d_ws, size_t ws_size,
                              hipStream_t stream)
{
    const float* hidden = (const float*)d_in[0];
    const float* corr   = (const float*)d_in[1];
    const int*   nei    = (const int*)d_in[2];
    const float* W_rela = (const float*)d_in[3];
    const float* b_rela = (const float*)d_in[4];
    const float* W_att  = (const float*)d_in[5];
    const float* b_att  = (const float*)d_in[6];
    float* ws  = (float*)d_ws;
    float* out = (float*)d_out;

    proj_kernel<<<PP / 4, 256, 0, stream>>>(hidden, W_att, b_att, ws);
    social_kernel<<<PP / ROWS, TPB, 0, stream>>>(hidden, corr, nei, W_rela,
                                                 b_rela, W_att, ws, out);
}